// Round 10
// baseline (235.313 us; speedup 1.0000x reference)
//
#include <hip/hip_runtime.h>

// out[b,o,n] = max_d |x[b,d,n] - w[o,d]| + bias[o]
// B=64, CIN=1024, COUT=1024, N=49. Pixels P = B*N = 3136.
//
// Round-10: balance VALU / LDS-pipe / wave-supply, and PIN the pipeline.
//  - w via LDS broadcast (ds_read is IN-ORDER on lgkmcnt -> counted waits, unlike
//    s_load whose OOO return forces a draining lgkmcnt(0) -- r5/6/9 failure).
//  - PIX=4 pixels/lane x CPW=4 channels/wave: per-tile compute 192 cyc vs
//    4 broadcast ds_read_b128 -> per-CU LDS pipe <= 1.0 utilization (r8 at PIX=1
//    was 4x oversubscribed).
//  - grid 128x13 = 1664 blocks = 13 waves/CU: TLP restored (r9 had 1.6 waves/SIMD).
//  - x: depth-2 prefetch in a 4-slot rotation (16 tiles/chunk % 4 == 0 -> slot
//    indices are chunk-invariant compile-time constants; rule-#20 safe).
//  - w: 2-slot rotation within chunk; staging global->reg at chunk start,
//    ds_write at chunk end (T14 split), ONE barrier per chunk.
//  - sched_barrier(0) between each tile's prefetch-issues and its compute:
//    r5-r9 disasm evidence (VGPR 32/52/56 << declared buffers) showed the
//    compiler collapsing the double-buffers and re-serializing.

typedef float v2f __attribute__((ext_vector_type(2)));
typedef float v4f __attribute__((ext_vector_type(4)));

constexpr int CIN  = 1024;
constexpr int COUT = 1024;
constexpr int NN   = 49;
constexpr int P    = 3136;
constexpr int CPW  = 4;              // channels per wave
constexpr int WPB  = 2;              // waves per block (128 threads)
constexpr int CPB  = CPW * WPB;      // 8 channels per block
constexpr int PIX  = 4;              // pixels per lane
constexpr int PT   = 64 * PIX;       // 256 pixels per tile
constexpr int NPT  = 13;             // 12 full + 1 ragged (64 px)
constexpr int KC   = 64;             // k per LDS chunk
constexpr int NCH  = CIN / KC;       // 16 chunks
constexpr int TPC  = KC / 4;         // 16 k-tiles per chunk
constexpr int NTL  = CIN / 4;        // 256 k-tiles

#define PKSUB(d, wp, xp) \
    asm("v_pk_add_f32 %0, %1, %2 neg_lo:[0,1] neg_hi:[0,1]" \
        : "=v"(d) : "v"(wp), "v"(xp))
#define AMAX3(a, lo, hi) \
    asm("v_max3_f32 %0, %0, |%1|, |%2|" : "+v"(a) : "v"(lo), "v"(hi))

__global__ __launch_bounds__(128) void ndist_kernel(
    const float* __restrict__ x, const float* __restrict__ w,
    const float* __restrict__ bias, float* __restrict__ out)
{
    __shared__ float wsm[2][CPB * KC];   // 2 x 2 KB

    const int t    = threadIdx.x;
    const int lane = t & 63;
    const int wid  = __builtin_amdgcn_readfirstlane(t >> 6);

    const int o0b   = blockIdx.x * CPB;        // block channel base
    const int o0    = o0b + wid * CPW;         // wave channel base
    const int pbase = blockIdx.y * PT;         // tile pixel base

    // pixel slots: validity is lane-independent (all bases multiples of 64)
    int bb[PIX], nn_[PIX];
    const float* xp[PIX];
#pragma unroll
    for (int i = 0; i < PIX; ++i) {
        const bool valid = (pbase + i * 64) < P;                    // uniform
        const int  pi    = (valid ? pbase + i * 64 : pbase) + lane; // clamp reads
        bb[i]  = pi / NN;
        nn_[i] = pi - bb[i] * NN;
        xp[i]  = x + (size_t)bb[i] * (CIN * NN) + nn_[i];
    }

    // staging: 512 floats/chunk, thread t covers 4 consecutive (1 dwordx4)
    const int sch = t >> 4;                    // channel 0..7
    const int sk  = (t & 15) * 4;              // k 0..60
    const float* __restrict__ gsrc = w + (size_t)(o0b + sch) * CIN + sk;
    const int ldst = sch * KC + sk;

    float acc[CPW][PIX];
#pragma unroll
    for (int c = 0; c < CPW; ++c)
#pragma unroll
        for (int i = 0; i < PIX; ++i) acc[c][i] = 0.0f;   // |diff| >= 0

    v2f xb[4][PIX][2];   // 4-slot x rotation (64 VGPR)
    v2f wb[2][CPW][2];   // 2-slot w rotation (16 VGPR)

#define LOAD_X(slot, kt) do {                                      \
        _Pragma("unroll")                                          \
        for (int i = 0; i < PIX; ++i) {                            \
            float a0 = xp[i][((kt) * 4 + 0) * NN];                 \
            float a1 = xp[i][((kt) * 4 + 1) * NN];                 \
            float a2 = xp[i][((kt) * 4 + 2) * NN];                 \
            float a3 = xp[i][((kt) * 4 + 3) * NN];                 \
            xb[slot][i][0] = (v2f){a0, a1};                        \
            xb[slot][i][1] = (v2f){a2, a3};                        \
        }                                                          \
    } while (0)

    // wave-uniform address -> ds_read_b128 broadcast (counted lgkmcnt)
#define LOAD_W(slot, buf, j) do {                                  \
        _Pragma("unroll")                                          \
        for (int c = 0; c < CPW; ++c) {                            \
            v4f q = *(const v4f*)&wsm[buf][(wid * CPW + c) * KC + (j) * 4]; \
            wb[slot][c][0] = (v2f){q.x, q.y};                      \
            wb[slot][c][1] = (v2f){q.z, q.w};                      \
        }                                                          \
    } while (0)

    // 32 pk + 32 max3 per tile (~192 SIMD-cyc of independent VALU)
#define COMPUTE(xs, wsl) do {                                      \
        _Pragma("unroll")                                          \
        for (int c = 0; c < CPW; ++c)                              \
        _Pragma("unroll")                                          \
        for (int i = 0; i < PIX; ++i) {                            \
            v2f d0, d1;                                            \
            PKSUB(d0, wb[wsl][c][0], xb[xs][i][0]);                \
            PKSUB(d1, wb[wsl][c][1], xb[xs][i][1]);                \
            AMAX3(acc[c][i], d0.x, d0.y);                          \
            AMAX3(acc[c][i], d1.x, d1.y);                          \
        }                                                          \
    } while (0)

    // prologue: stage chunk 0; preload x tiles 0,1 into slots 0,1
    {
        v4f r = *(const v4f*)gsrc;
        *(v4f*)&wsm[0][ldst] = r;
    }
    __syncthreads();
    LOAD_X(0, 0);
    LOAD_X(1, 1);

    for (int ch = 0; ch < NCH; ++ch) {
        const int buf = ch & 1;

        // T14: issue next chunk's staging load now, write it after compute
        v4f preg;
        if (ch + 1 < NCH) preg = *(const v4f*)(gsrc + (ch + 1) * KC);

        LOAD_W(0, buf, 0);

#pragma unroll
        for (int j = 0; j < TPC; ++j) {
            // prefetch: next tile's w (within chunk), x two tiles ahead
            if (j + 1 < TPC) LOAD_W((j + 1) & 1, buf, j + 1);
            const int gt = (ch * TPC + j + 2) & (NTL - 1);  // wrap: harmless
            LOAD_X((j + 2) & 3, gt);
            __builtin_amdgcn_sched_barrier(0);   // pin: issues above, compute below
            COMPUTE(j & 3, j & 1);
        }

        if (ch + 1 < NCH) *(v4f*)&wsm[buf ^ 1][ldst] = preg;
        __syncthreads();
    }

    // epilogue: slot validity is block-uniform
#pragma unroll
    for (int i = 0; i < PIX; ++i) {
        if ((pbase + i * 64) < P) {
#pragma unroll
            for (int c = 0; c < CPW; ++c) {
                const int o = o0 + c;
                out[((size_t)bb[i] * COUT + o) * NN + nn_[i]] = acc[c][i] + bias[o];
            }
        }
    }
}

extern "C" void kernel_launch(void* const* d_in, const int* in_sizes, int n_in,
                              void* d_out, int out_size, void* d_ws, size_t ws_size,
                              hipStream_t stream) {
    const float* x    = (const float*)d_in[0];
    const float* w    = (const float*)d_in[1];
    const float* bias = (const float*)d_in[2];
    float* out        = (float*)d_out;

    dim3 grid(COUT / CPB, NPT);   // (128 channel-groups, 13 pixel-tiles) = 1664 blocks
    ndist_kernel<<<grid, 128, 0, stream>>>(x, w, bias, out);
}

// Round 11
// 154.492 us; speedup vs baseline: 1.5231x; 1.5231x over previous
//
#include <hip/hip_runtime.h>

// out[b,o,n] = max_d |x[b,d,n] - w[o,d]| + bias[o]
// B=64, CIN=1024, COUT=1024, N=49. Pixels P = B*N = 3136.
//
// Round-11: hand-pipelined s_load for w. Rounds 5-10 showed the one structural
// stall: the compiler must drain lgkmcnt(0) (SMEM is OOO) before using w-buffer
// A, and by then buffer B's prefetch is outstanding -> full ~250cyc L2 latency
// exposed per 4-k stage. Fix: issue w loads as OPAQUE asm-volatile
// s_load_dwordx4 (compiler's waitcnt pass ignores them) and place our own
// s_waitcnt lgkmcnt(0) AFTER the compute block that covers the latency:
//   [issue W(t+1)] [compute t] [drain] [issue W(t+2)] [compute t+1] [drain]...
// PIX=2 pixels/lane doubles compute per drain (~64 VALU instrs); 64-thread
// blocks, grid 128x25=3200 -> 3.125 waves/SIMD TLP + 4% tail. x on the normal
// compiler-managed VMEM path (in-order counted vmcnt, overlaps fine).
// Inner mix: v_pk_add_f32(neg) + v_max3(|.|,|.|) = 1.0 instr/update.

typedef float v2f  __attribute__((ext_vector_type(2)));
typedef float v4sf __attribute__((ext_vector_type(4)));

constexpr int CIN  = 1024;
constexpr int COUT = 1024;
constexpr int NN   = 49;
constexpr int P    = 3136;
constexpr int CPW  = 8;                  // channels per wave
constexpr int PIX  = 2;                  // pixels per lane
constexpr int PT   = 64 * PIX;           // 128 pixels per tile
constexpr int NPT  = (P + PT - 1) / PT;  // 25 (last tile: 64 px)
constexpr int NTL  = CIN / 4;            // 256 k-stages

#define PKSUB(d, wp, xp) \
    asm("v_pk_add_f32 %0, %1, %2 neg_lo:[0,1] neg_hi:[0,1]" \
        : "=v"(d) : "s"(wp), "v"(xp))
#define AMAX3(a, lo, hi) \
    asm("v_max3_f32 %0, %0, |%1|, |%2|" : "+v"(a) : "v"(lo), "v"(hi))

// 8 channels x 4 k: immediate offsets c*CIN*4 = c*0x1000 off one base.
// asm volatile keeps issue order; outputs are opaque defs (no compiler waits).
#define ISSUE_W(buf, ptr) do {                                               \
    asm volatile("s_load_dwordx4 %0, %1, 0x0"    : "=s"(buf[0]) : "s"(ptr)); \
    asm volatile("s_load_dwordx4 %0, %1, 0x1000" : "=s"(buf[1]) : "s"(ptr)); \
    asm volatile("s_load_dwordx4 %0, %1, 0x2000" : "=s"(buf[2]) : "s"(ptr)); \
    asm volatile("s_load_dwordx4 %0, %1, 0x3000" : "=s"(buf[3]) : "s"(ptr)); \
    asm volatile("s_load_dwordx4 %0, %1, 0x4000" : "=s"(buf[4]) : "s"(ptr)); \
    asm volatile("s_load_dwordx4 %0, %1, 0x5000" : "=s"(buf[5]) : "s"(ptr)); \
    asm volatile("s_load_dwordx4 %0, %1, 0x6000" : "=s"(buf[6]) : "s"(ptr)); \
    asm volatile("s_load_dwordx4 %0, %1, 0x7000" : "=s"(buf[7]) : "s"(ptr)); \
} while (0)

#define SDRAIN() asm volatile("s_waitcnt lgkmcnt(0)" ::: "memory")

__global__ __launch_bounds__(64) void ndist_kernel(
    const float* __restrict__ x, const float* __restrict__ w,
    const float* __restrict__ bias, float* __restrict__ out)
{
    const int lane  = threadIdx.x;            // 0..63
    const int o0    = blockIdx.x * CPW;       // wave channel base
    const int pbase = blockIdx.y * PT;        // tile pixel base

    // pixel slots; validity is lane-independent (bases all multiples of 64)
    int bb[PIX], nn_[PIX];
    const float* xp[PIX];
#pragma unroll
    for (int i = 0; i < PIX; ++i) {
        const bool valid = (pbase + i * 64) < P;                    // uniform
        const int  pi    = (valid ? pbase + i * 64 : pbase) + lane; // clamp reads
        bb[i]  = pi / NN;
        nn_[i] = pi - bb[i] * NN;
        xp[i]  = x + (size_t)bb[i] * (CIN * NN) + nn_[i];
    }

    const float* wb = w + (size_t)o0 * CIN;   // uniform base for asm s_loads

    float acc[CPW][PIX];
#pragma unroll
    for (int c = 0; c < CPW; ++c)
#pragma unroll
        for (int i = 0; i < PIX; ++i) acc[c][i] = 0.0f;   // |diff| >= 0

    v2f  xA[PIX][2], xB[PIX][2];   // x k-pairs, double-buffered (VGPR)
    v4sf wS0[8], wS1[8];           // w stages, ping-pong (SGPR, asm-managed)

#define LOAD_X(dst, kt) do {                                   \
        _Pragma("unroll")                                      \
        for (int i = 0; i < PIX; ++i) {                        \
            float a0 = xp[i][((kt) * 4 + 0) * NN];             \
            float a1 = xp[i][((kt) * 4 + 1) * NN];             \
            float a2 = xp[i][((kt) * 4 + 2) * NN];             \
            float a3 = xp[i][((kt) * 4 + 3) * NN];             \
            dst[i][0] = (v2f){a0, a1};                         \
            dst[i][1] = (v2f){a2, a3};                         \
        }                                                      \
    } while (0)

    // 32 PKSUB + 32 AMAX3 per stage (~64 independent VALU instrs)
#define COMPUTE(xv, wbuf) do {                                 \
        _Pragma("unroll")                                      \
        for (int c = 0; c < CPW; ++c) {                        \
            v2f wlo = __builtin_shufflevector(wbuf[c], wbuf[c], 0, 1); \
            v2f whi = __builtin_shufflevector(wbuf[c], wbuf[c], 2, 3); \
            _Pragma("unroll")                                  \
            for (int i = 0; i < PIX; ++i) {                    \
                v2f d0, d1;                                    \
                PKSUB(d0, wlo, xv[i][0]);                      \
                PKSUB(d1, whi, xv[i][1]);                      \
                AMAX3(acc[c][i], d0.x, d0.y);                  \
                AMAX3(acc[c][i], d1.x, d1.y);                  \
            }                                                  \
        }                                                      \
    } while (0)

    // prologue: stage 0's w + x, drain once
    ISSUE_W(wS0, wb);
    LOAD_X(xA, 0);
    SDRAIN();

    // main loop: stages kt, kt+1 with issue->compute->drain pipelining.
    // Last two stages peeled (no wrap loads -> no OOB, no index clamps).
    for (int kt = 0; kt < NTL - 2; kt += 2) {
        const float* w1 = wb + (size_t)(kt + 1) * 4;
        ISSUE_W(wS1, w1);                 // w for stage kt+1
        LOAD_X(xB, kt + 1);               // x for stage kt+1 (VMEM, counted)
        COMPUTE(xA, wS0);                 // stage kt  (covers W(kt+1) latency)
        SDRAIN();                         // W(kt+1) ready

        const float* w2 = wb + (size_t)(kt + 2) * 4;
        ISSUE_W(wS0, w2);                 // w for stage kt+2
        LOAD_X(xA, kt + 2);               // x for stage kt+2
        COMPUTE(xB, wS1);                 // stage kt+1
        SDRAIN();                         // W(kt+2) ready
    }
    {   // stages 254, 255
        const float* w1 = wb + (size_t)(NTL - 1) * 4;
        ISSUE_W(wS1, w1);
        LOAD_X(xB, NTL - 1);
        COMPUTE(xA, wS0);                 // stage 254
        SDRAIN();
        COMPUTE(xB, wS1);                 // stage 255
    }

    // epilogue: slot validity is block-uniform
#pragma unroll
    for (int i = 0; i < PIX; ++i) {
        if ((pbase + i * 64) < P) {
#pragma unroll
            for (int c = 0; c < CPW; ++c) {
                const int o = o0 + c;
                out[((size_t)bb[i] * COUT + o) * NN + nn_[i]] = acc[c][i] + bias[o];
            }
        }
    }
}

extern "C" void kernel_launch(void* const* d_in, const int* in_sizes, int n_in,
                              void* d_out, int out_size, void* d_ws, size_t ws_size,
                              hipStream_t stream) {
    const float* x    = (const float*)d_in[0];
    const float* w    = (const float*)d_in[1];
    const float* bias = (const float*)d_in[2];
    float* out        = (float*)d_out;

    dim3 grid(COUT / CPW, NPT);   // (128 channel-groups, 25 pixel-tiles) = 3200 blocks
    ndist_kernel<<<grid, 64, 0, stream>>>(x, w, bias, out);
}